// Round 2
// baseline (9.334 us; speedup 1.0000x reference)
//
#include <hip/hip_runtime.h>

// Q=3, R=128, V=64, EPS=0.4999999
// flat_idx = (i0*R^2 + i1*R + i2) % R == i2 % R  (R^2, R both ≡ 0 mod R), so
// the 8 gathers collapse to 2 distinct rows: round(saw2 ± EPS).
// Weight factorization: w_i = sum_j d[j][sign_ij]; summing over the 4 rows
// sharing each i2-candidate gives W± = 2(d0+ + d0-) + 2(d1+ + d1-) + 4*d2±.

#define RR 128
#define VV 64
#define KB_EPS 0.4999999f

__global__ __launch_bounds__(64) void kb_kernel(
    const float* __restrict__ query,
    const float* __restrict__ storage,
    float* __restrict__ out)
{
    const int v = threadIdx.x;  // 0..63

    // Per-dim rounded-neighbor weights d±[j] = 1 - |round(saw_j ± EPS) - saw_j|
    float dsum01 = 0.0f;     // (d0+ + d0-) + (d1+ + d1-)
    float d2p, d2m;
    int   i2p, i2m;
#pragma unroll
    for (int j = 0; j < 3; ++j) {
        const float q   = query[j];
        const float saw = (q - floorf(q)) * (float)RR;
        const float rp  = rintf(saw + KB_EPS);   // half-to-even, matches jnp.round
        const float rm  = rintf(saw - KB_EPS);
        const float dp  = 1.0f - fabsf(rp - saw);
        const float dm  = 1.0f - fabsf(rm - saw);
        if (j < 2) {
            dsum01 += dp + dm;
        } else {
            d2p = dp; d2m = dm;
            i2p = (int)rp; i2m = (int)rm;       // in [0,128]
        }
    }
    // faithful python-style mod
    int fp = i2p % RR; if (fp < 0) fp += RR;
    int fm = i2m % RR; if (fm < 0) fm += RR;

    const float Wp = 2.0f * dsum01 + 4.0f * d2p;
    const float Wm = 2.0f * dsum01 + 4.0f * d2m;

    const float acc = Wp * storage[(size_t)fp * VV + v]
                    + Wm * storage[(size_t)fm * VV + v];

    out[v] = acc * (1.0f / 3.0f);
}

extern "C" void kernel_launch(void* const* d_in, const int* in_sizes, int n_in,
                              void* d_out, int out_size, void* d_ws, size_t ws_size,
                              hipStream_t stream) {
    const float* query   = (const float*)d_in[0];
    const float* storage = (const float*)d_in[1];
    float* out = (float*)d_out;
    kb_kernel<<<1, 64, 0, stream>>>(query, storage, out);
}